// Round 2
// baseline (3319.410 us; speedup 1.0000x reference)
//
#include <hip/hip_runtime.h>
#include <hip/hip_bf16.h>

typedef __hip_bfloat16 bf16;

#define NEG_SLOPE 0.01f
#define FGW 0.1f

__device__ __forceinline__ float b2f(bf16 v) { return __bfloat162float(v); }

// flagged boundary load: isbf=1 -> data is bf16, else f32
__device__ __forceinline__ float ldf(const void* p, size_t i, int isbf) {
    return isbf ? b2f(((const bf16*)p)[i]) : ((const float*)p)[i];
}

// ordered-uint encoding for float atomicMax (monotonic over all finite floats)
__device__ __forceinline__ unsigned f2o(float f) {
    unsigned u = __float_as_uint(f);
    return (u & 0x80000000u) ? ~u : (u | 0x80000000u);
}
__device__ __forceinline__ float o2f(unsigned e) {
    return (e & 0x80000000u) ? __uint_as_float(e & 0x7FFFFFFFu) : __uint_as_float(~e);
}

__device__ __forceinline__ float waveReduceSum(float v) {
#pragma unroll
    for (int o = 32; o > 0; o >>= 1) v += __shfl_down(v, o, 64);
    return v;
}

#define ATOMIC_ADD_F32(p, v) unsafeAtomicAdd((p), (v))

// ---------------- dtype detector: 1 block, 64 threads ----------------
// Examine first 256 uint16 halves of x interpreted as bf16. True-bf16 N(0,1)
// data never has exponent >= 0xBF (|v| >= 2^64). True-f32 data's low halves
// are random mantissa bits -> such exponents appear w.p. ~1 - 1e-16.
__global__ void k_detect(const unsigned short* __restrict__ xr, int* __restrict__ flag) {
    int t = threadIdx.x;
    int big = 0;
    for (int i = t; i < 256; i += 64) {
        int ex = (xr[i] >> 7) & 0xFF;
        if (ex >= 0xBF) big = 1;
    }
    unsigned long long m = __ballot(big);
    if (t == 0) *flag = (m == 0ull) ? 1 : 0;  // 1 => bf16 tensors
}

// ---------------- GEMM1: h1[N,256] = x[N,128] @ W1[128,256] ----------------
__global__ __launch_bounds__(256) void k_gemm1(const void* __restrict__ x,
                                               const void* __restrict__ W,
                                               float* __restrict__ h1, int N,
                                               const int* __restrict__ flag) {
    const int isbf = *flag;
    __shared__ float xs[16][128];
    const int row0 = blockIdx.x * 16;
    const int t = threadIdx.x;
#pragma unroll
    for (int i = 0; i < 8; i++) {
        int idx = t + i * 256;
        int r = idx >> 7, c = idx & 127;
        xs[r][c] = ldf(x, (size_t)(row0 + r) * 128 + c, isbf);
    }
    __syncthreads();
    const int j = t;  // column 0..255
    float acc[16];
#pragma unroll
    for (int r = 0; r < 16; r++) acc[r] = 0.f;
    for (int k = 0; k < 128; k += 4) {
        float w0 = ldf(W, (size_t)(k + 0) * 256 + j, isbf);
        float w1 = ldf(W, (size_t)(k + 1) * 256 + j, isbf);
        float w2 = ldf(W, (size_t)(k + 2) * 256 + j, isbf);
        float w3 = ldf(W, (size_t)(k + 3) * 256 + j, isbf);
#pragma unroll
        for (int r = 0; r < 16; r++) {
            float4 xv = *reinterpret_cast<const float4*>(&xs[r][k]);
            acc[r] += xv.x * w0 + xv.y * w1 + xv.z * w2 + xv.w * w3;
        }
    }
#pragma unroll
    for (int r = 0; r < 16; r++)
        h1[(size_t)(row0 + r) * 256 + j] = acc[r];
}

// ---------------- per-(node,head) attention halves, layer1 ----------------
__global__ __launch_bounds__(256) void k_stats1(const float* __restrict__ h1,
                                                const void* __restrict__ attl,
                                                const void* __restrict__ attr,
                                                float* __restrict__ al, float* __restrict__ ar,
                                                int N, const int* __restrict__ flag) {
    const int isbf = *flag;
    const int n = blockIdx.x;          // one block per node
    const int h = threadIdx.x >> 6;    // wave per head
    const int c = threadIdx.x & 63;
    float v = h1[(size_t)n * 256 + h * 64 + c];
    float sl = waveReduceSum(v * ldf(attl, h * 64 + c, isbf));
    float sr = waveReduceSum(v * ldf(attr, h * 64 + c, isbf));
    if (c == 0) { al[n * 4 + h] = sl; ar[n * 4 + h] = sr; }
}

// ---------------- reward-weight sum, layer1 (x col 127, stride 128) ----------------
__global__ __launch_bounds__(256) void k_rwsum1(const void* __restrict__ x, float* __restrict__ s,
                                                int N, const int* __restrict__ flag) {
    const int isbf = *flag;
    __shared__ float red[256];
    int n = blockIdx.x * 256 + threadIdx.x;
    float r = 0.f;
    if (n < N) {
        float a = fabsf(ldf(x, (size_t)n * 128 + 127, isbf));
        r = 1.f / (a + 1e-6f);
    }
    red[threadIdx.x] = r;
    __syncthreads();
    for (int o = 128; o > 0; o >>= 1) {
        if (threadIdx.x < o) red[threadIdx.x] += red[threadIdx.x + o];
        __syncthreads();
    }
    if (threadIdx.x == 0) ATOMIC_ADD_F32(s, red[0]);
}

__global__ __launch_bounds__(256) void k_log1(const void* __restrict__ x, const float* __restrict__ s,
                                              float* __restrict__ logrw, int N,
                                              const int* __restrict__ flag) {
    const int isbf = *flag;
    int n = blockIdx.x * 256 + threadIdx.x;
    if (n >= N) return;
    float a = fabsf(ldf(x, (size_t)n * 128 + 127, isbf));
    float r = 1.f / (a + 1e-6f);
    logrw[n] = logf(r / fmaxf(*s, 1e-12f));
}

// ---------------- edge pass A1: alpha + atomic max per (dst,head) ----------------
__global__ __launch_bounds__(256) void k_edgeA1(const int* __restrict__ ei,
                                                const float* __restrict__ al, const float* __restrict__ ar,
                                                const float* __restrict__ logrw,
                                                float* __restrict__ alpha, unsigned* __restrict__ maxb, int E) {
    int tid = blockIdx.x * 256 + threadIdx.x;
    if (tid >= E * 4) return;
    int e = tid >> 2, h = tid & 3;
    int s = ei[e], d = ei[E + e];
    float a = al[d * 4 + h] + ar[s * 4 + h];
    a = (a > 0.f) ? a : NEG_SLOPE * a;
    a += FGW * logrw[s];
    alpha[tid] = a;
    atomicMax(&maxb[d * 4 + h], f2o(a));
}

// ---------------- edge pass B1: exp + atomic sum ----------------
__global__ __launch_bounds__(256) void k_edgeB1(const int* __restrict__ ei,
                                                float* __restrict__ alpha,
                                                const unsigned* __restrict__ maxb,
                                                float* __restrict__ sumb, int E) {
    int tid = blockIdx.x * 256 + threadIdx.x;
    if (tid >= E * 4) return;
    int e = tid >> 2, h = tid & 3;
    int d = ei[E + e];
    float m = o2f(maxb[d * 4 + h]);
    float ex = expf(alpha[tid] - m);
    alpha[tid] = ex;
    ATOMIC_ADD_F32(&sumb[d * 4 + h], ex);
}

// ---------------- edge pass C1: normalize + scatter-aggregate (wave per edge) ----------------
__global__ __launch_bounds__(256) void k_edgeC1(const int* __restrict__ ei,
                                                const float* __restrict__ alpha,
                                                const float* __restrict__ sumb,
                                                const float* __restrict__ h1,
                                                float* __restrict__ out1, int E) {
    int e = blockIdx.x * 4 + (threadIdx.x >> 6);
    if (e >= E) return;
    int lane = threadIdx.x & 63;
    int s = ei[e], d = ei[E + e];
    int h = lane >> 4;  // (lane*4)>>6
    float coef = alpha[e * 4 + h] / (sumb[d * 4 + h] + 1e-16f);
    float4 hv = *reinterpret_cast<const float4*>(&h1[(size_t)s * 256 + lane * 4]);
    float* op = &out1[(size_t)d * 256 + lane * 4];
    ATOMIC_ADD_F32(op + 0, coef * hv.x);
    ATOMIC_ADD_F32(op + 1, coef * hv.y);
    ATOMIC_ADD_F32(op + 2, coef * hv.z);
    ATOMIC_ADD_F32(op + 3, coef * hv.w);
}

// ---------------- elementwise ELU (in place) ----------------
__global__ __launch_bounds__(256) void k_elu(float* __restrict__ v, int n) {
    int i = blockIdx.x * 256 + threadIdx.x;
    if (i >= n) return;
    float x = v[i];
    v[i] = (x > 0.f) ? x : expm1f(x);
}

// ---------------- GEMM2: h2[N,64] = x2[N,256](f32) @ W2[256,64] ----------------
__global__ __launch_bounds__(256) void k_gemm2(const float* __restrict__ x2,
                                               const void* __restrict__ W,
                                               float* __restrict__ h2, int N,
                                               const int* __restrict__ flag) {
    const int isbf = *flag;
    __shared__ float xs[16][256];
    const int row0 = blockIdx.x * 16;
    const int t = threadIdx.x;
#pragma unroll
    for (int i = 0; i < 16; i++) {
        int idx = t + i * 256;
        int r = idx >> 8, c = idx & 255;
        xs[r][c] = x2[(size_t)(row0 + r) * 256 + c];
    }
    __syncthreads();
    const int j = t & 63, rg = t >> 6;  // wave rg handles rows rg*4..rg*4+3
    float acc[4] = {0.f, 0.f, 0.f, 0.f};
    for (int k = 0; k < 256; k += 4) {
        float w0 = ldf(W, (size_t)(k + 0) * 64 + j, isbf);
        float w1 = ldf(W, (size_t)(k + 1) * 64 + j, isbf);
        float w2 = ldf(W, (size_t)(k + 2) * 64 + j, isbf);
        float w3 = ldf(W, (size_t)(k + 3) * 64 + j, isbf);
#pragma unroll
        for (int i = 0; i < 4; i++) {
            float4 xv = *reinterpret_cast<const float4*>(&xs[rg * 4 + i][k]);
            acc[i] += xv.x * w0 + xv.y * w1 + xv.z * w2 + xv.w * w3;
        }
    }
#pragma unroll
    for (int i = 0; i < 4; i++)
        h2[(size_t)(row0 + rg * 4 + i) * 64 + j] = acc[i];
}

// ---------------- per-node attention halves, layer2 (H=1) ----------------
__global__ __launch_bounds__(256) void k_stats2(const float* __restrict__ h2,
                                                const void* __restrict__ attl,
                                                const void* __restrict__ attr,
                                                float* __restrict__ al, float* __restrict__ ar,
                                                int N, const int* __restrict__ flag) {
    const int isbf = *flag;
    int n = blockIdx.x * 4 + (threadIdx.x >> 6);
    int c = threadIdx.x & 63;
    float v = (n < N) ? h2[(size_t)n * 64 + c] : 0.f;
    float sl = waveReduceSum(v * ldf(attl, c, isbf));
    float sr = waveReduceSum(v * ldf(attr, c, isbf));
    if (n < N && c == 0) { al[n] = sl; ar[n] = sr; }
}

// ---------------- reward-weight sum, layer2 (x2 f32, col 255) ----------------
__global__ __launch_bounds__(256) void k_rwsum2(const float* __restrict__ x2, float* __restrict__ s, int N) {
    __shared__ float red[256];
    int n = blockIdx.x * 256 + threadIdx.x;
    float r = 0.f;
    if (n < N) {
        float a = fabsf(x2[(size_t)n * 256 + 255]);
        r = 1.f / (a + 1e-6f);
    }
    red[threadIdx.x] = r;
    __syncthreads();
    for (int o = 128; o > 0; o >>= 1) {
        if (threadIdx.x < o) red[threadIdx.x] += red[threadIdx.x + o];
        __syncthreads();
    }
    if (threadIdx.x == 0) ATOMIC_ADD_F32(s, red[0]);
}

__global__ __launch_bounds__(256) void k_log2(const float* __restrict__ x2, const float* __restrict__ s,
                                              float* __restrict__ logrw, int N) {
    int n = blockIdx.x * 256 + threadIdx.x;
    if (n >= N) return;
    float a = fabsf(x2[(size_t)n * 256 + 255]);
    float r = 1.f / (a + 1e-6f);
    logrw[n] = logf(r / fmaxf(*s, 1e-12f));
}

// ---------------- edge passes, layer2 (H=1) ----------------
__global__ __launch_bounds__(256) void k_edgeA2(const int* __restrict__ ei,
                                                const float* __restrict__ al, const float* __restrict__ ar,
                                                const float* __restrict__ logrw,
                                                float* __restrict__ alpha, unsigned* __restrict__ maxb, int E) {
    int e = blockIdx.x * 256 + threadIdx.x;
    if (e >= E) return;
    int s = ei[e], d = ei[E + e];
    float a = al[d] + ar[s];
    a = (a > 0.f) ? a : NEG_SLOPE * a;
    a += FGW * logrw[s];
    alpha[e] = a;
    atomicMax(&maxb[d], f2o(a));
}

__global__ __launch_bounds__(256) void k_edgeB2(const int* __restrict__ ei,
                                                float* __restrict__ alpha,
                                                const unsigned* __restrict__ maxb,
                                                float* __restrict__ sumb, int E) {
    int e = blockIdx.x * 256 + threadIdx.x;
    if (e >= E) return;
    int d = ei[E + e];
    float m = o2f(maxb[d]);
    float ex = expf(alpha[e] - m);
    alpha[e] = ex;
    ATOMIC_ADD_F32(&sumb[d], ex);
}

__global__ __launch_bounds__(256) void k_edgeC2(const int* __restrict__ ei,
                                                const float* __restrict__ alpha,
                                                const float* __restrict__ sumb,
                                                const float* __restrict__ h2,
                                                float* __restrict__ out2, int E) {
    int e = blockIdx.x * 4 + (threadIdx.x >> 6);
    if (e >= E) return;
    int lane = threadIdx.x & 63;
    int s = ei[e], d = ei[E + e];
    float coef = alpha[e] / (sumb[d] + 1e-16f);
    ATOMIC_ADD_F32(&out2[(size_t)d * 64 + lane], coef * h2[(size_t)s * 64 + lane]);
}

// ---------------- final: elu + fc, flagged output dtype ----------------
__global__ __launch_bounds__(256) void k_final(const float* __restrict__ out2,
                                               const void* __restrict__ fcw,
                                               const void* __restrict__ fcb,
                                               void* __restrict__ y, int N,
                                               const int* __restrict__ flag) {
    const int isbf = *flag;
    int n = blockIdx.x * 4 + (threadIdx.x >> 6);
    int c = threadIdx.x & 63;
    float v = (n < N) ? out2[(size_t)n * 64 + c] : 0.f;
    v = (v > 0.f) ? v : expm1f(v);
    float sacc = waveReduceSum(v * ldf(fcw, c, isbf));
    if (n < N && c == 0) {
        float r = sacc + ldf(fcb, 0, isbf);
        if (isbf) ((bf16*)y)[n] = __float2bfloat16(r);
        else      ((float*)y)[n] = r;
    }
}

extern "C" void kernel_launch(void* const* d_in, const int* in_sizes, int n_in,
                              void* d_out, int out_size, void* d_ws, size_t ws_size,
                              hipStream_t stream) {
    const void* x     = d_in[0];
    const int*  ei    = (const int*)d_in[1];
    const void* W1    = d_in[2];
    const void* attl1 = d_in[3];
    const void* attr1 = d_in[4];
    const void* W2    = d_in[5];
    const void* attl2 = d_in[6];
    const void* attr2 = d_in[7];
    const void* fcw   = d_in[8];
    const void* fcb   = d_in[9];

    const int N = in_sizes[0] / 128;  // 50000
    const int E = in_sizes[1] / 2;    // 800000

    // ---- workspace layout (fp32 elements) ----
    float* p = (float*)d_ws;
    float* h1    = p; p += (size_t)N * 256;   // region0: h1; later h2 (N*64) + out2 (N*64)
    float* x2    = p; p += (size_t)N * 256;   // region1: out1 accum -> elu in place -> x2
    float* alpha = p; p += (size_t)E * 4;     // layer1 [E,4]; layer2 reuses first E
    float* al1   = p; p += (size_t)N * 4;
    float* ar1   = p; p += (size_t)N * 4;
    float* logrw = p; p += (size_t)N;
    unsigned* maxb = (unsigned*)p; p += (size_t)N * 4;
    float* sumb  = p; p += (size_t)N * 4;
    float* sscal = p; p += 4;                 // [0]=rw sum L1, [1]=rw sum L2, [2]=dtype flag
    int* dflag = (int*)(sscal + 2);

    // layer2 overlays (regions dead by the time these are used)
    float* h2   = h1;
    float* out2 = h1 + (size_t)N * 64;
    float* al2 = al1; float* ar2 = ar1; float* logrw2 = logrw;
    unsigned* maxb2 = maxb; float* sumb2 = sumb; float* alpha2 = alpha;

    // ---- zero accumulators (ws is re-poisoned to 0xAA each call) ----
    hipMemsetAsync(x2,    0, (size_t)N * 256 * 4, stream);
    hipMemsetAsync(maxb,  0, (size_t)N * 4 * 4, stream);
    hipMemsetAsync(sumb,  0, (size_t)N * 4 * 4, stream);
    hipMemsetAsync(sscal, 0, 16, stream);

    // ---- dtype detection ----
    k_detect<<<1, 64, 0, stream>>>((const unsigned short*)x, dflag);

    // ---- layer 1 ----
    k_gemm1<<<N / 16, 256, 0, stream>>>(x, W1, h1, N, dflag);
    k_stats1<<<N, 256, 0, stream>>>(h1, attl1, attr1, al1, ar1, N, dflag);
    k_rwsum1<<<(N + 255) / 256, 256, 0, stream>>>(x, &sscal[0], N, dflag);
    k_log1<<<(N + 255) / 256, 256, 0, stream>>>(x, &sscal[0], logrw, N, dflag);
    k_edgeA1<<<(E * 4 + 255) / 256, 256, 0, stream>>>(ei, al1, ar1, logrw, alpha, maxb, E);
    k_edgeB1<<<(E * 4 + 255) / 256, 256, 0, stream>>>(ei, alpha, maxb, sumb, E);
    k_edgeC1<<<(E + 3) / 4, 256, 0, stream>>>(ei, alpha, sumb, h1, x2, E);
    k_elu<<<(N * 256 + 255) / 256, 256, 0, stream>>>(x2, N * 256);

    // ---- layer-2 accumulator zeroing (after layer-1 region0 contents are dead) ----
    hipMemsetAsync(out2,  0, (size_t)N * 64 * 4, stream);
    hipMemsetAsync(maxb2, 0, (size_t)N * 4, stream);
    hipMemsetAsync(sumb2, 0, (size_t)N * 4, stream);

    // ---- layer 2 ----
    k_gemm2<<<N / 16, 256, 0, stream>>>(x2, W2, h2, N, dflag);
    k_stats2<<<(N + 3) / 4, 256, 0, stream>>>(h2, attl2, attr2, al2, ar2, N, dflag);
    k_rwsum2<<<(N + 255) / 256, 256, 0, stream>>>(x2, &sscal[1], N);
    k_log2<<<(N + 255) / 256, 256, 0, stream>>>(x2, &sscal[1], logrw2, N);
    k_edgeA2<<<(E + 255) / 256, 256, 0, stream>>>(ei, al2, ar2, logrw2, alpha2, maxb2, E);
    k_edgeB2<<<(E + 255) / 256, 256, 0, stream>>>(ei, alpha2, maxb2, sumb2, E);
    k_edgeC2<<<(E + 3) / 4, 256, 0, stream>>>(ei, alpha2, sumb2, h2, out2, E);

    // ---- final ----
    k_final<<<(N + 3) / 4, 256, 0, stream>>>(out2, fcw, fcb, d_out, N, dflag);
}

// Round 3
// 744.652 us; speedup vs baseline: 4.4577x; 4.4577x over previous
//
#include <hip/hip_runtime.h>
#include <hip/hip_bf16.h>

typedef __hip_bfloat16 bf16;

#define NEG_SLOPE 0.01f
#define FGW 0.1f

__device__ __forceinline__ float b2f(bf16 v) { return __bfloat162float(v); }

// flagged boundary load: isbf=1 -> data is bf16, else f32
__device__ __forceinline__ float ldf(const void* p, size_t i, int isbf) {
    return isbf ? b2f(((const bf16*)p)[i]) : ((const float*)p)[i];
}

__device__ __forceinline__ float waveReduceSum(float v) {
#pragma unroll
    for (int o = 32; o > 0; o >>= 1) v += __shfl_down(v, o, 64);
    return v;
}

#define ATOMIC_ADD_F32(p, v) unsafeAtomicAdd((p), (v))

// ---------------- dtype detector: 1 block, 64 threads ----------------
__global__ void k_detect(const unsigned short* __restrict__ xr, int* __restrict__ flag) {
    int t = threadIdx.x;
    int big = 0;
    for (int i = t; i < 256; i += 64) {
        int ex = (xr[i] >> 7) & 0xFF;
        if (ex >= 0xBF) big = 1;   // |bf16| >= 2^64 impossible for N(0,1) data
    }
    unsigned long long m = __ballot(big);
    if (t == 0) *flag = (m == 0ull) ? 1 : 0;  // 1 => tensors are bf16
}

// ---------------- CSR build ----------------
__global__ __launch_bounds__(256) void k_deg(const int* __restrict__ ei, int* __restrict__ deg, int E) {
    int e = blockIdx.x * 256 + threadIdx.x;
    if (e >= E) return;
    atomicAdd(&deg[ei[E + e]], 1);
}

// single block, 256 threads, 16 elems/thread per chunk
__global__ __launch_bounds__(256) void k_scan(const int* __restrict__ deg, int* __restrict__ rowptr, int N) {
    __shared__ int partial[256];
    __shared__ int s_carry;
    const int t = threadIdx.x;
    if (t == 0) s_carry = 0;
    __syncthreads();
    for (int base = 0; base < N; base += 4096) {
        int v[16];
        int lsum = 0;
        int i0 = base + t * 16;
#pragma unroll
        for (int k = 0; k < 16; k++) {
            int i = i0 + k;
            v[k] = (i < N) ? deg[i] : 0;
            lsum += v[k];
        }
        partial[t] = lsum;
        __syncthreads();
        for (int o = 1; o < 256; o <<= 1) {
            int add = (t >= o) ? partial[t - o] : 0;
            __syncthreads();
            partial[t] += add;
            __syncthreads();
        }
        int excl = s_carry + partial[t] - lsum;
#pragma unroll
        for (int k = 0; k < 16; k++) {
            int i = i0 + k;
            if (i < N) rowptr[i] = excl;
            excl += v[k];
        }
        __syncthreads();
        if (t == 255) s_carry += partial[255];
        __syncthreads();
    }
    if (t == 0) rowptr[N] = s_carry;
}

__global__ __launch_bounds__(256) void k_scatter(const int* __restrict__ ei, const int* __restrict__ rowptr,
                                                 int* __restrict__ cursor,
                                                 int* __restrict__ csr_src, int* __restrict__ csr_eid, int E) {
    int e = blockIdx.x * 256 + threadIdx.x;
    if (e >= E) return;
    int d = ei[E + e];
    int pos = atomicAdd(&cursor[d], 1);
    int slot = rowptr[d] + pos;
    csr_src[slot] = ei[e];
    csr_eid[slot] = e;
}

// ---------------- GEMM1: h1[N,256] = x[N,128] @ W1[128,256] ----------------
__global__ __launch_bounds__(256) void k_gemm1(const void* __restrict__ x,
                                               const void* __restrict__ W,
                                               float* __restrict__ h1, int N,
                                               const int* __restrict__ flag) {
    const int isbf = *flag;
    __shared__ float xs[16][128];
    const int row0 = blockIdx.x * 16;
    const int t = threadIdx.x;
#pragma unroll
    for (int i = 0; i < 8; i++) {
        int idx = t + i * 256;
        int r = idx >> 7, c = idx & 127;
        xs[r][c] = ldf(x, (size_t)(row0 + r) * 128 + c, isbf);
    }
    __syncthreads();
    const int j = t;  // column 0..255
    float acc[16];
#pragma unroll
    for (int r = 0; r < 16; r++) acc[r] = 0.f;
    for (int k = 0; k < 128; k += 4) {
        float w0 = ldf(W, (size_t)(k + 0) * 256 + j, isbf);
        float w1 = ldf(W, (size_t)(k + 1) * 256 + j, isbf);
        float w2 = ldf(W, (size_t)(k + 2) * 256 + j, isbf);
        float w3 = ldf(W, (size_t)(k + 3) * 256 + j, isbf);
#pragma unroll
        for (int r = 0; r < 16; r++) {
            float4 xv = *reinterpret_cast<const float4*>(&xs[r][k]);
            acc[r] += xv.x * w0 + xv.y * w1 + xv.z * w2 + xv.w * w3;
        }
    }
#pragma unroll
    for (int r = 0; r < 16; r++)
        h1[(size_t)(row0 + r) * 256 + j] = acc[r];
}

// ---------------- per-(node,head) attention halves, layer1 ----------------
__global__ __launch_bounds__(256) void k_stats1(const float* __restrict__ h1,
                                                const void* __restrict__ attl,
                                                const void* __restrict__ attr,
                                                float* __restrict__ al, float* __restrict__ ar,
                                                int N, const int* __restrict__ flag) {
    const int isbf = *flag;
    const int n = blockIdx.x;
    const int h = threadIdx.x >> 6;
    const int c = threadIdx.x & 63;
    float v = h1[(size_t)n * 256 + h * 64 + c];
    float sl = waveReduceSum(v * ldf(attl, h * 64 + c, isbf));
    float sr = waveReduceSum(v * ldf(attr, h * 64 + c, isbf));
    if (c == 0) { al[n * 4 + h] = sl; ar[n * 4 + h] = sr; }
}

// ---------------- reward weights, layer1 ----------------
__global__ __launch_bounds__(256) void k_rwsum1(const void* __restrict__ x, float* __restrict__ s,
                                                int N, const int* __restrict__ flag) {
    const int isbf = *flag;
    __shared__ float red[256];
    int n = blockIdx.x * 256 + threadIdx.x;
    float r = 0.f;
    if (n < N) {
        float a = fabsf(ldf(x, (size_t)n * 128 + 127, isbf));
        r = 1.f / (a + 1e-6f);
    }
    red[threadIdx.x] = r;
    __syncthreads();
    for (int o = 128; o > 0; o >>= 1) {
        if (threadIdx.x < o) red[threadIdx.x] += red[threadIdx.x + o];
        __syncthreads();
    }
    if (threadIdx.x == 0) ATOMIC_ADD_F32(s, red[0]);
}

__global__ __launch_bounds__(256) void k_log1(const void* __restrict__ x, const float* __restrict__ s,
                                              float* __restrict__ logrw, int N,
                                              const int* __restrict__ flag) {
    const int isbf = *flag;
    int n = blockIdx.x * 256 + threadIdx.x;
    if (n >= N) return;
    float a = fabsf(ldf(x, (size_t)n * 128 + 127, isbf));
    float r = 1.f / (a + 1e-6f);
    logrw[n] = logf(r / fmaxf(*s, 1e-12f));
}

// ---------------- per-edge alpha (pre-softmax), layer1: no atomics ----------------
__global__ __launch_bounds__(256) void k_alphaE1(const int* __restrict__ ei,
                                                 const float* __restrict__ al, const float* __restrict__ ar,
                                                 const float* __restrict__ logrw,
                                                 float* __restrict__ alpha, int E) {
    int tid = blockIdx.x * 256 + threadIdx.x;
    if (tid >= E * 4) return;
    int e = tid >> 2, h = tid & 3;
    int s = ei[e], d = ei[E + e];
    float a = al[d * 4 + h] + ar[s * 4 + h];
    a = (a > 0.f) ? a : NEG_SLOPE * a;
    a += FGW * logrw[s];
    alpha[tid] = a;
}

// ---------------- layer1 aggregation: wave per dst node, CSR walk ----------------
// out = elu( (sum_e exp(a_e - m) * h1[src_e]) / (sum_e exp(a_e - m) + 1e-16) )
__global__ __launch_bounds__(256) void k_agg1(const int* __restrict__ rowptr,
                                              const int* __restrict__ csr_src,
                                              const int* __restrict__ csr_eid,
                                              const float* __restrict__ alpha,
                                              const float* __restrict__ h1,
                                              float* __restrict__ x2, int N) {
    int d = blockIdx.x * 4 + (threadIdx.x >> 6);
    if (d >= N) return;
    int lane = threadIdx.x & 63;
    int h = lane >> 4;                 // head for this lane's 4 features
    int beg = rowptr[d], end = rowptr[d + 1];
    float m = -INFINITY;
    for (int i = beg; i < end; i++)
        m = fmaxf(m, alpha[csr_eid[i] * 4 + h]);
    float sum = 0.f;
    float4 acc = {0.f, 0.f, 0.f, 0.f};
    for (int i = beg; i < end; i++) {
        int s = csr_src[i];
        float e = expf(alpha[csr_eid[i] * 4 + h] - m);
        sum += e;
        float4 hv = *reinterpret_cast<const float4*>(&h1[(size_t)s * 256 + lane * 4]);
        acc.x += e * hv.x; acc.y += e * hv.y; acc.z += e * hv.z; acc.w += e * hv.w;
    }
    float inv = 1.f / (sum + 1e-16f);
    float4 o;
    o.x = acc.x * inv; o.y = acc.y * inv; o.z = acc.z * inv; o.w = acc.w * inv;
    o.x = (o.x > 0.f) ? o.x : expm1f(o.x);
    o.y = (o.y > 0.f) ? o.y : expm1f(o.y);
    o.z = (o.z > 0.f) ? o.z : expm1f(o.z);
    o.w = (o.w > 0.f) ? o.w : expm1f(o.w);
    *reinterpret_cast<float4*>(&x2[(size_t)d * 256 + lane * 4]) = o;
}

// ---------------- GEMM2: h2[N,64] = x2[N,256](f32) @ W2[256,64] ----------------
__global__ __launch_bounds__(256) void k_gemm2(const float* __restrict__ x2,
                                               const void* __restrict__ W,
                                               float* __restrict__ h2, int N,
                                               const int* __restrict__ flag) {
    const int isbf = *flag;
    __shared__ float xs[16][256];
    const int row0 = blockIdx.x * 16;
    const int t = threadIdx.x;
#pragma unroll
    for (int i = 0; i < 16; i++) {
        int idx = t + i * 256;
        int r = idx >> 8, c = idx & 255;
        xs[r][c] = x2[(size_t)(row0 + r) * 256 + c];
    }
    __syncthreads();
    const int j = t & 63, rg = t >> 6;
    float acc[4] = {0.f, 0.f, 0.f, 0.f};
    for (int k = 0; k < 256; k += 4) {
        float w0 = ldf(W, (size_t)(k + 0) * 64 + j, isbf);
        float w1 = ldf(W, (size_t)(k + 1) * 64 + j, isbf);
        float w2 = ldf(W, (size_t)(k + 2) * 64 + j, isbf);
        float w3 = ldf(W, (size_t)(k + 3) * 64 + j, isbf);
#pragma unroll
        for (int i = 0; i < 4; i++) {
            float4 xv = *reinterpret_cast<const float4*>(&xs[rg * 4 + i][k]);
            acc[i] += xv.x * w0 + xv.y * w1 + xv.z * w2 + xv.w * w3;
        }
    }
#pragma unroll
    for (int i = 0; i < 4; i++)
        h2[(size_t)(row0 + rg * 4 + i) * 64 + j] = acc[i];
}

// ---------------- per-node attention halves, layer2 (H=1) ----------------
__global__ __launch_bounds__(256) void k_stats2(const float* __restrict__ h2,
                                                const void* __restrict__ attl,
                                                const void* __restrict__ attr,
                                                float* __restrict__ al, float* __restrict__ ar,
                                                int N, const int* __restrict__ flag) {
    const int isbf = *flag;
    int n = blockIdx.x * 4 + (threadIdx.x >> 6);
    int c = threadIdx.x & 63;
    float v = (n < N) ? h2[(size_t)n * 64 + c] : 0.f;
    float sl = waveReduceSum(v * ldf(attl, c, isbf));
    float sr = waveReduceSum(v * ldf(attr, c, isbf));
    if (n < N && c == 0) { al[n] = sl; ar[n] = sr; }
}

// ---------------- reward weights, layer2 ----------------
__global__ __launch_bounds__(256) void k_rwsum2(const float* __restrict__ x2, float* __restrict__ s, int N) {
    __shared__ float red[256];
    int n = blockIdx.x * 256 + threadIdx.x;
    float r = 0.f;
    if (n < N) {
        float a = fabsf(x2[(size_t)n * 256 + 255]);
        r = 1.f / (a + 1e-6f);
    }
    red[threadIdx.x] = r;
    __syncthreads();
    for (int o = 128; o > 0; o >>= 1) {
        if (threadIdx.x < o) red[threadIdx.x] += red[threadIdx.x + o];
        __syncthreads();
    }
    if (threadIdx.x == 0) ATOMIC_ADD_F32(s, red[0]);
}

__global__ __launch_bounds__(256) void k_log2(const float* __restrict__ x2, const float* __restrict__ s,
                                              float* __restrict__ logrw, int N) {
    int n = blockIdx.x * 256 + threadIdx.x;
    if (n >= N) return;
    float a = fabsf(x2[(size_t)n * 256 + 255]);
    float r = 1.f / (a + 1e-6f);
    logrw[n] = logf(r / fmaxf(*s, 1e-12f));
}

// ---------------- per-edge alpha, layer2 (H=1) ----------------
__global__ __launch_bounds__(256) void k_alphaE2(const int* __restrict__ ei,
                                                 const float* __restrict__ al, const float* __restrict__ ar,
                                                 const float* __restrict__ logrw,
                                                 float* __restrict__ alpha, int E) {
    int e = blockIdx.x * 256 + threadIdx.x;
    if (e >= E) return;
    int s = ei[e], d = ei[E + e];
    float a = al[d] + ar[s];
    a = (a > 0.f) ? a : NEG_SLOPE * a;
    a += FGW * logrw[s];
    alpha[e] = a;
}

// ---------------- layer2 aggregation + ELU + FC -> y (fused final) ----------------
__global__ __launch_bounds__(256) void k_agg2(const int* __restrict__ rowptr,
                                              const int* __restrict__ csr_src,
                                              const int* __restrict__ csr_eid,
                                              const float* __restrict__ alpha,
                                              const float* __restrict__ h2,
                                              const void* __restrict__ fcw,
                                              const void* __restrict__ fcb,
                                              void* __restrict__ y, int N,
                                              const int* __restrict__ flag) {
    const int isbf = *flag;
    int d = blockIdx.x * 4 + (threadIdx.x >> 6);
    if (d >= N) return;
    int lane = threadIdx.x & 63;
    int beg = rowptr[d], end = rowptr[d + 1];
    float m = -INFINITY;
    for (int i = beg; i < end; i++)
        m = fmaxf(m, alpha[csr_eid[i]]);
    float sum = 0.f, acc = 0.f;
    for (int i = beg; i < end; i++) {
        int s = csr_src[i];
        float e = expf(alpha[csr_eid[i]] - m);
        sum += e;
        acc += e * h2[(size_t)s * 64 + lane];
    }
    float v = acc / (sum + 1e-16f);
    v = (v > 0.f) ? v : expm1f(v);
    float r = waveReduceSum(v * ldf(fcw, lane, isbf));
    if (lane == 0) {
        float o = r + ldf(fcb, 0, isbf);
        if (isbf) ((bf16*)y)[d] = __float2bfloat16(o);
        else      ((float*)y)[d] = o;
    }
}

extern "C" void kernel_launch(void* const* d_in, const int* in_sizes, int n_in,
                              void* d_out, int out_size, void* d_ws, size_t ws_size,
                              hipStream_t stream) {
    const void* x     = d_in[0];
    const int*  ei    = (const int*)d_in[1];
    const void* W1    = d_in[2];
    const void* attl1 = d_in[3];
    const void* attr1 = d_in[4];
    const void* W2    = d_in[5];
    const void* attl2 = d_in[6];
    const void* attr2 = d_in[7];
    const void* fcw   = d_in[8];
    const void* fcb   = d_in[9];

    const int N = in_sizes[0] / 128;  // 50000
    const int E = in_sizes[1] / 2;    // 800000

    // ---- workspace layout (4-byte elements), ~124 MB total ----
    float* p = (float*)d_ws;
    float* h1     = p; p += (size_t)N * 256;   // 51.2 MB; h2 overlays (N*64)
    float* x2     = p; p += (size_t)N * 256;   // 51.2 MB
    float* alpha1 = p; p += (size_t)E * 4;     // 12.8 MB; alpha2 overlays (E)
    float* al1    = p; p += (size_t)N * 4;
    float* ar1    = p; p += (size_t)N * 4;
    float* logrw  = p; p += (size_t)N;
    int* rowptr   = (int*)p; p += (size_t)N + 1;
    int* deg      = (int*)p; p += (size_t)N;
    int* cursor   = (int*)p; p += (size_t)N;
    int* csr_src  = (int*)p; p += (size_t)E;   // 3.2 MB
    int* csr_eid  = (int*)p; p += (size_t)E;   // 3.2 MB
    float* sscal  = p; p += 4;                 // [0]=rwsum L1, [1]=rwsum L2, [2]=dtype flag
    int* dflag = (int*)(sscal + 2);

    float* h2 = h1;                 // layer2 overlays
    float* alpha2 = alpha1;
    float* al2 = al1; float* ar2 = ar1; float* logrw2 = logrw;

    // ---- zero the small accumulators (ws is re-poisoned each call) ----
    hipMemsetAsync(deg,    0, (size_t)N * 4, stream);
    hipMemsetAsync(cursor, 0, (size_t)N * 4, stream);
    hipMemsetAsync(sscal,  0, 16, stream);

    k_detect<<<1, 64, 0, stream>>>((const unsigned short*)x, dflag);

    // ---- CSR build over dst ----
    k_deg<<<(E + 255) / 256, 256, 0, stream>>>(ei, deg, E);
    k_scan<<<1, 256, 0, stream>>>(deg, rowptr, N);
    k_scatter<<<(E + 255) / 256, 256, 0, stream>>>(ei, rowptr, cursor, csr_src, csr_eid, E);

    // ---- layer 1 ----
    k_gemm1<<<N / 16, 256, 0, stream>>>(x, W1, h1, N, dflag);
    k_stats1<<<N, 256, 0, stream>>>(h1, attl1, attr1, al1, ar1, N, dflag);
    k_rwsum1<<<(N + 255) / 256, 256, 0, stream>>>(x, &sscal[0], N, dflag);
    k_log1<<<(N + 255) / 256, 256, 0, stream>>>(x, &sscal[0], logrw, N, dflag);
    k_alphaE1<<<(E * 4 + 255) / 256, 256, 0, stream>>>(ei, al1, ar1, logrw, alpha1, E);
    k_agg1<<<(N + 3) / 4, 256, 0, stream>>>(rowptr, csr_src, csr_eid, alpha1, h1, x2, N);

    // ---- layer 2 ----
    k_gemm2<<<N / 16, 256, 0, stream>>>(x2, W2, h2, N, dflag);
    k_stats2<<<(N + 3) / 4, 256, 0, stream>>>(h2, attl2, attr2, al2, ar2, N, dflag);
    k_rwsum2<<<(N + 255) / 256, 256, 0, stream>>>(x2, &sscal[1], N);
    k_log2<<<(N + 255) / 256, 256, 0, stream>>>(x2, &sscal[1], logrw2, N);
    k_alphaE2<<<(E + 255) / 256, 256, 0, stream>>>(ei, al2, ar2, logrw2, alpha2, E);
    k_agg2<<<(N + 3) / 4, 256, 0, stream>>>(rowptr, csr_src, csr_eid, alpha2, h2, fcw, fcb, d_out, N, dflag);
}

// Round 4
// 621.876 us; speedup vs baseline: 5.3377x; 1.1974x over previous
//
#include <hip/hip_runtime.h>
#include <hip/hip_bf16.h>

typedef __hip_bfloat16 bf16;

#define NEG_SLOPE 0.01f
#define FGW 0.1f

__device__ __forceinline__ float b2f(bf16 v) { return __bfloat162float(v); }

// flagged boundary load: isbf=1 -> data is bf16, else f32
__device__ __forceinline__ float ldf(const void* p, size_t i, int isbf) {
    return isbf ? b2f(((const bf16*)p)[i]) : ((const float*)p)[i];
}

__device__ __forceinline__ float waveReduceSum(float v) {
#pragma unroll
    for (int o = 32; o > 0; o >>= 1) v += __shfl_down(v, o, 64);
    return v;
}

#define ATOMIC_ADD_F32(p, v) unsafeAtomicAdd((p), (v))

// ---------------- dtype detector: 1 block, 64 threads ----------------
__global__ void k_detect(const unsigned short* __restrict__ xr, int* __restrict__ flag) {
    int t = threadIdx.x;
    int big = 0;
    for (int i = t; i < 256; i += 64) {
        int ex = (xr[i] >> 7) & 0xFF;
        if (ex >= 0xBF) big = 1;   // |bf16| >= 2^64 impossible for N(0,1) data
    }
    unsigned long long m = __ballot(big);
    if (t == 0) *flag = (m == 0ull) ? 1 : 0;  // 1 => tensors are bf16
}

// ---------------- CSR build ----------------
__global__ __launch_bounds__(256) void k_deg(const int* __restrict__ ei, int* __restrict__ deg, int E) {
    int e = blockIdx.x * 256 + threadIdx.x;
    if (e >= E) return;
    atomicAdd(&deg[ei[E + e]], 1);
}

// single block, 256 threads, 16 elems/thread per chunk
__global__ __launch_bounds__(256) void k_scan(const int* __restrict__ deg, int* __restrict__ rowptr, int N) {
    __shared__ int partial[256];
    __shared__ int s_carry;
    const int t = threadIdx.x;
    if (t == 0) s_carry = 0;
    __syncthreads();
    for (int base = 0; base < N; base += 4096) {
        int v[16];
        int lsum = 0;
        int i0 = base + t * 16;
#pragma unroll
        for (int k = 0; k < 16; k++) {
            int i = i0 + k;
            v[k] = (i < N) ? deg[i] : 0;
            lsum += v[k];
        }
        partial[t] = lsum;
        __syncthreads();
        for (int o = 1; o < 256; o <<= 1) {
            int add = (t >= o) ? partial[t - o] : 0;
            __syncthreads();
            partial[t] += add;
            __syncthreads();
        }
        int excl = s_carry + partial[t] - lsum;
#pragma unroll
        for (int k = 0; k < 16; k++) {
            int i = i0 + k;
            if (i < N) rowptr[i] = excl;
            excl += v[k];
        }
        __syncthreads();
        if (t == 255) s_carry += partial[255];
        __syncthreads();
    }
    if (t == 0) rowptr[N] = s_carry;
}

__global__ __launch_bounds__(256) void k_scatter(const int* __restrict__ ei, const int* __restrict__ rowptr,
                                                 int* __restrict__ cursor, int* __restrict__ csr_src, int E) {
    int e = blockIdx.x * 256 + threadIdx.x;
    if (e >= E) return;
    int d = ei[E + e];
    int pos = atomicAdd(&cursor[d], 1);
    csr_src[rowptr[d] + pos] = ei[e];
}

// ---------------- GEMM1 fused: h1 = x@W1 ; al1/ar1 wave-reduced ; logr + rwsum ----------------
__global__ __launch_bounds__(256) void k_gemm1f(const void* __restrict__ x,
                                                const void* __restrict__ W,
                                                const void* __restrict__ attl,
                                                const void* __restrict__ attr,
                                                float* __restrict__ h1,
                                                float* __restrict__ al1, float* __restrict__ ar1,
                                                float* __restrict__ logr, float* __restrict__ rwS,
                                                int N, const int* __restrict__ flag) {
    const int isbf = *flag;
    __shared__ float xs[16][128];
    __shared__ float rpart[16];
    const int row0 = blockIdx.x * 16;
    const int t = threadIdx.x;
#pragma unroll
    for (int i = 0; i < 8; i++) {
        int idx = t + i * 256;
        int r = idx >> 7, c = idx & 127;
        xs[r][c] = ldf(x, (size_t)(row0 + r) * 128 + c, isbf);
    }
    __syncthreads();
    const int j = t;  // column 0..255; wave w = j>>6 == head
    float acc[16];
#pragma unroll
    for (int r = 0; r < 16; r++) acc[r] = 0.f;
    for (int k = 0; k < 128; k += 4) {
        float w0 = ldf(W, (size_t)(k + 0) * 256 + j, isbf);
        float w1 = ldf(W, (size_t)(k + 1) * 256 + j, isbf);
        float w2 = ldf(W, (size_t)(k + 2) * 256 + j, isbf);
        float w3 = ldf(W, (size_t)(k + 3) * 256 + j, isbf);
#pragma unroll
        for (int r = 0; r < 16; r++) {
            float4 xv = *reinterpret_cast<const float4*>(&xs[r][k]);
            acc[r] += xv.x * w0 + xv.y * w1 + xv.z * w2 + xv.w * w3;
        }
    }
#pragma unroll
    for (int r = 0; r < 16; r++)
        h1[(size_t)(row0 + r) * 256 + j] = acc[r];

    // fused stats: wave w reduces head w (cols w*64..w*64+63)
    const int w = t >> 6, lane = t & 63;
    float avl = ldf(attl, j, isbf);
    float avr = ldf(attr, j, isbf);
#pragma unroll
    for (int r = 0; r < 16; r++) {
        float sl = waveReduceSum(acc[r] * avl);
        float sr = waveReduceSum(acc[r] * avr);
        if (lane == 0) {
            al1[(row0 + r) * 4 + w] = sl;
            ar1[(row0 + r) * 4 + w] = sr;
        }
    }
    // fused reward weight: x col 127 is in LDS
    if (t < 16) {
        float a = fabsf(xs[t][127]);
        float rr = 1.f / (a + 1e-6f);
        logr[row0 + t] = logf(rr);
        rpart[t] = rr;
    }
    __syncthreads();
    if (t == 0) {
        float s = 0.f;
#pragma unroll
        for (int i = 0; i < 16; i++) s += rpart[i];
        ATOMIC_ADD_F32(rwS, s);
    }
}

// ---------------- layer1 aggregation: online softmax, alpha on the fly ----------------
// wave per dst node; out = elu( sum_e exp(a_e - m) h1[src_e] / (sum_e exp(a_e - m) + 1e-16) )
__global__ __launch_bounds__(256) void k_agg1(const int* __restrict__ rowptr,
                                              const int* __restrict__ csr_src,
                                              const float* __restrict__ al1,
                                              const float* __restrict__ ar1,
                                              const float* __restrict__ logr,
                                              const float* __restrict__ rwS,
                                              const float* __restrict__ h1,
                                              float* __restrict__ x2, int N) {
    int d = blockIdx.x * 4 + (threadIdx.x >> 6);
    if (d >= N) return;
    int lane = threadIdx.x & 63;
    int h = lane >> 4;                 // head for this lane's 4 features
    float logS = logf(fmaxf(*rwS, 1e-12f));
    float al_h = al1[d * 4 + h];
    int beg = rowptr[d], end = rowptr[d + 1];
    float m = -INFINITY, sum = 0.f;
    float4 acc = {0.f, 0.f, 0.f, 0.f};
    for (int i = beg; i < end; i++) {
        int s = csr_src[i];
        float a = al_h + ar1[s * 4 + h];
        a = (a > 0.f) ? a : NEG_SLOPE * a;
        a += FGW * (logr[s] - logS);
        float mn = fmaxf(m, a);
        float f = expf(m - mn);        // 0 on first edge (m=-inf)
        float e = expf(a - mn);
        sum = sum * f + e;
        float4 hv = *reinterpret_cast<const float4*>(&h1[(size_t)s * 256 + lane * 4]);
        acc.x = acc.x * f + e * hv.x;
        acc.y = acc.y * f + e * hv.y;
        acc.z = acc.z * f + e * hv.z;
        acc.w = acc.w * f + e * hv.w;
        m = mn;
    }
    float inv = 1.f / (sum + 1e-16f);
    float4 o;
    o.x = acc.x * inv; o.y = acc.y * inv; o.z = acc.z * inv; o.w = acc.w * inv;
    o.x = (o.x > 0.f) ? o.x : expm1f(o.x);
    o.y = (o.y > 0.f) ? o.y : expm1f(o.y);
    o.z = (o.z > 0.f) ? o.z : expm1f(o.z);
    o.w = (o.w > 0.f) ? o.w : expm1f(o.w);
    *reinterpret_cast<float4*>(&x2[(size_t)d * 256 + lane * 4]) = o;
}

// ---------------- GEMM2 fused: h2 = x2@W2 ; al2/ar2 ; logr2 + rwsum2 ----------------
__global__ __launch_bounds__(256) void k_gemm2f(const float* __restrict__ x2,
                                                const void* __restrict__ W,
                                                const void* __restrict__ attl,
                                                const void* __restrict__ attr,
                                                float* __restrict__ h2,
                                                float* __restrict__ al2, float* __restrict__ ar2,
                                                float* __restrict__ logr2, float* __restrict__ rwS2,
                                                int N, const int* __restrict__ flag) {
    const int isbf = *flag;
    __shared__ float xs[16][256];
    __shared__ float rpart[16];
    const int row0 = blockIdx.x * 16;
    const int t = threadIdx.x;
#pragma unroll
    for (int i = 0; i < 16; i++) {
        int idx = t + i * 256;
        int r = idx >> 8, c = idx & 255;
        xs[r][c] = x2[(size_t)(row0 + r) * 256 + c];
    }
    __syncthreads();
    const int j = t & 63, rg = t >> 6;   // wave rg handles rows rg*4..rg*4+3
    float acc[4] = {0.f, 0.f, 0.f, 0.f};
    for (int k = 0; k < 256; k += 4) {
        float w0 = ldf(W, (size_t)(k + 0) * 64 + j, isbf);
        float w1 = ldf(W, (size_t)(k + 1) * 64 + j, isbf);
        float w2 = ldf(W, (size_t)(k + 2) * 64 + j, isbf);
        float w3 = ldf(W, (size_t)(k + 3) * 64 + j, isbf);
#pragma unroll
        for (int i = 0; i < 4; i++) {
            float4 xv = *reinterpret_cast<const float4*>(&xs[rg * 4 + i][k]);
            acc[i] += xv.x * w0 + xv.y * w1 + xv.z * w2 + xv.w * w3;
        }
    }
    float avl = ldf(attl, j, isbf);
    float avr = ldf(attr, j, isbf);
#pragma unroll
    for (int i = 0; i < 4; i++) {
        int row = row0 + rg * 4 + i;
        h2[(size_t)row * 64 + j] = acc[i];
        float sl = waveReduceSum(acc[i] * avl);
        float sr = waveReduceSum(acc[i] * avr);
        if (j == 0) { al2[row] = sl; ar2[row] = sr; }
    }
    // fused reward weight: x2 col 255 in LDS
    if (t < 16) {
        float a = fabsf(xs[t][255]);
        float rr = 1.f / (a + 1e-6f);
        logr2[row0 + t] = logf(rr);
        rpart[t] = rr;
    }
    __syncthreads();
    if (t == 0) {
        float s = 0.f;
#pragma unroll
        for (int i = 0; i < 16; i++) s += rpart[i];
        ATOMIC_ADD_F32(rwS2, s);
    }
}

// ---------------- layer2 aggregation + ELU + FC -> y (online softmax) ----------------
__global__ __launch_bounds__(256) void k_agg2(const int* __restrict__ rowptr,
                                              const int* __restrict__ csr_src,
                                              const float* __restrict__ al2,
                                              const float* __restrict__ ar2,
                                              const float* __restrict__ logr2,
                                              const float* __restrict__ rwS2,
                                              const float* __restrict__ h2,
                                              const void* __restrict__ fcw,
                                              const void* __restrict__ fcb,
                                              void* __restrict__ y, int N,
                                              const int* __restrict__ flag) {
    const int isbf = *flag;
    int d = blockIdx.x * 4 + (threadIdx.x >> 6);
    if (d >= N) return;
    int lane = threadIdx.x & 63;
    float logS = logf(fmaxf(*rwS2, 1e-12f));
    float al_d = al2[d];
    int beg = rowptr[d], end = rowptr[d + 1];
    float m = -INFINITY, sum = 0.f, acc = 0.f;
    for (int i = beg; i < end; i++) {
        int s = csr_src[i];
        float a = al_d + ar2[s];
        a = (a > 0.f) ? a : NEG_SLOPE * a;
        a += FGW * (logr2[s] - logS);
        float mn = fmaxf(m, a);
        float f = expf(m - mn);
        float e = expf(a - mn);
        sum = sum * f + e;
        acc = acc * f + e * h2[(size_t)s * 64 + lane];
        m = mn;
    }
    float v = acc / (sum + 1e-16f);
    v = (v > 0.f) ? v : expm1f(v);
    float r = waveReduceSum(v * ldf(fcw, lane, isbf));
    if (lane == 0) {
        float o = r + ldf(fcb, 0, isbf);
        if (isbf) ((bf16*)y)[d] = __float2bfloat16(o);
        else      ((float*)y)[d] = o;
    }
}

extern "C" void kernel_launch(void* const* d_in, const int* in_sizes, int n_in,
                              void* d_out, int out_size, void* d_ws, size_t ws_size,
                              hipStream_t stream) {
    const void* x     = d_in[0];
    const int*  ei    = (const int*)d_in[1];
    const void* W1    = d_in[2];
    const void* attl1 = d_in[3];
    const void* attr1 = d_in[4];
    const void* W2    = d_in[5];
    const void* attl2 = d_in[6];
    const void* attr2 = d_in[7];
    const void* fcw   = d_in[8];
    const void* fcb   = d_in[9];

    const int N = in_sizes[0] / 128;  // 50000
    const int E = in_sizes[1] / 2;    // 800000

    // ---- workspace layout (4-byte elements), ~110 MB ----
    float* p = (float*)d_ws;
    float* h1     = p; p += (size_t)N * 256;   // 51.2 MB; h2 overlays (N*64)
    float* x2     = p; p += (size_t)N * 256;   // 51.2 MB
    float* al1    = p; p += (size_t)N * 4;
    float* ar1    = p; p += (size_t)N * 4;
    float* logr   = p; p += (size_t)N;
    float* al2    = p; p += (size_t)N;
    float* ar2    = p; p += (size_t)N;
    float* logr2  = p; p += (size_t)N;
    int* rowptr   = (int*)p; p += (size_t)N + 1;
    int* deg      = (int*)p; p += (size_t)N;   // deg+cursor zeroed in one memset
    int* cursor   = (int*)p; p += (size_t)N;
    int* csr_src  = (int*)p; p += (size_t)E;   // 3.2 MB
    float* sscal  = p; p += 4;                 // [0]=rwsum L1, [1]=rwsum L2, [2]=dtype flag
    int* dflag = (int*)(sscal + 2);

    float* h2 = h1;   // layer2 overlays h1 region (dead after agg1)

    // ---- zero small accumulators (ws is re-poisoned to 0xAA each call) ----
    hipMemsetAsync(deg,   0, (size_t)N * 2 * 4, stream);   // deg + cursor
    hipMemsetAsync(sscal, 0, 16, stream);

    k_detect<<<1, 64, 0, stream>>>((const unsigned short*)x, dflag);

    // ---- CSR build over dst ----
    k_deg<<<(E + 255) / 256, 256, 0, stream>>>(ei, deg, E);
    k_scan<<<1, 256, 0, stream>>>(deg, rowptr, N);
    k_scatter<<<(E + 255) / 256, 256, 0, stream>>>(ei, rowptr, cursor, csr_src, E);

    // ---- layer 1 ----
    k_gemm1f<<<N / 16, 256, 0, stream>>>(x, W1, attl1, attr1, h1, al1, ar1,
                                         logr, &sscal[0], N, dflag);
    k_agg1<<<(N + 3) / 4, 256, 0, stream>>>(rowptr, csr_src, al1, ar1, logr,
                                            &sscal[0], h1, x2, N);

    // ---- layer 2 ----
    k_gemm2f<<<N / 16, 256, 0, stream>>>(x2, W2, attl2, attr2, h2, al2, ar2,
                                         logr2, &sscal[1], N, dflag);
    k_agg2<<<(N + 3) / 4, 256, 0, stream>>>(rowptr, csr_src, al2, ar2, logr2,
                                            &sscal[1], h2, fcw, fcb, d_out, N, dflag);
}